// Round 1
// baseline (832.894 us; speedup 1.0000x reference)
//
#include <hip/hip_runtime.h>
#include <math.h>

#define CIN   96
#define HW_IN 3969     // 63*63
#define WIN   63
#define COUT  256
#define NPIX  900      // 30*30
#define WO    30
#define KTOT  2400     // CIN*5*5
#define NB    128

typedef short bf16x8 __attribute__((ext_vector_type(8)));
typedef float f32x4  __attribute__((ext_vector_type(4)));

__device__ __forceinline__ short f2bf(float f) {
  union { float f; unsigned u; } v; v.f = f;
  unsigned r = v.u + 0x7fffu + ((v.u >> 16) & 1u);  // RNE
  return (short)(r >> 16);
}

// ---- Stage 1: per-(b,ci) global average pool over 63x63 ----
__global__ __launch_bounds__(256) void pool_kernel(const float* __restrict__ x,
                                                   float* __restrict__ pooled) {
  const int ci = blockIdx.x;
  const int b  = blockIdx.y;
  const float* xc = x + ((size_t)b * CIN + ci) * HW_IN;
  const int tid = threadIdx.x, lane = tid & 63, wv = tid >> 6;
  float s = 0.f;
  // channel base offset mod 4 elements == ci mod 4 (96*3969 % 4 == 0, 3969 % 4 == 1)
  const int head = (4 - (ci & 3)) & 3;
  if (tid < head) s += xc[tid];
  const float4* x4 = (const float4*)(xc + head);
  const int n4 = (HW_IN - head) >> 2;
  for (int i = tid; i < n4; i += 256) { float4 v = x4[i]; s += (v.x + v.y) + (v.z + v.w); }
  const int done = head + (n4 << 2);
  if (tid < HW_IN - done) s += xc[done + tid];
  #pragma unroll
  for (int off = 32; off > 0; off >>= 1) s += __shfl_xor(s, off, 64);
  __shared__ float part[4];
  if (lane == 0) part[wv] = s;
  __syncthreads();
  if (tid == 0)
    pooled[(size_t)b * CIN + ci] = (part[0] + part[1] + part[2] + part[3]) * (1.0f / HW_IN);
}

// ---- Stage 2: attention MLP + softmax(logits / 31) ----
__global__ __launch_bounds__(64) void attn_kernel(const float* __restrict__ pooled,
                                                  const float* __restrict__ w1,
                                                  const float* __restrict__ w2,
                                                  float* __restrict__ att) {
  const int b = blockIdx.x;
  const int tid = threadIdx.x;
  __shared__ float hidden[24];
  const float* pb = pooled + (size_t)b * CIN;
  if (tid < 24) {
    float h = 0.f;
    const float* w1r = w1 + tid * CIN;
    for (int ci = 0; ci < CIN; ++ci) h += pb[ci] * w1r[ci];
    hidden[tid] = fmaxf(h, 0.f);
  }
  __syncthreads();
  if (tid == 0) {
    float l0 = 0.f, l1 = 0.f;
    for (int j = 0; j < 24; ++j) { l0 += hidden[j] * w2[j]; l1 += hidden[j] * w2[24 + j]; }
    l0 *= (1.0f / 31.0f); l1 *= (1.0f / 31.0f);
    const float m = fmaxf(l0, l1);
    const float e0 = expf(l0 - m), e1 = expf(l1 - m);
    const float inv = 1.0f / (e0 + e1);
    att[b * 2 + 0] = e0 * inv;
    att[b * 2 + 1] = e1 * inv;
  }
}

// ---- Stage 3: per-sample conv as implicit GEMM (bf16 MFMA 16x16x32) ----
// Per sample b: C[co, p] = sum_k (a0*Wc + a1*We)[co, k] * X[k, p],
// k = ci*25 + kh*5 + kw, p = oh*30 + ow, X[k,p] = x[b, ci, 2*oh+kh, 2*ow+kw].
__global__ __launch_bounds__(256) void conv_kernel(
    const float* __restrict__ x,
    const float* __restrict__ wc, const float* __restrict__ we,
    const float* __restrict__ bc, const float* __restrict__ be,
    const float* __restrict__ att, float* __restrict__ out) {
  const int b  = blockIdx.z;
  const int m0 = blockIdx.y * 128;   // Cout tile
  const int p0 = blockIdx.x * 128;   // pixel tile (last tile: only 4 of 128 valid)

  __shared__ short As[128][40];      // [m][k], +8 pad: conflict-free b128 frag reads
  __shared__ short Bs[128][40];      // [n][k]
  __shared__ int   koffAll[KTOT];    // im2col offset table: ci*3969 + kh*63 + kw
  __shared__ float biasS[128];

  const int tid  = threadIdx.x;
  const int wv   = tid >> 6, lane = tid & 63;
  const int quad = lane >> 4, lm = lane & 15;
  const int wm = (wv >> 1) * 64;     // wave's 64x64 sub-tile
  const int wn = (wv & 1) * 64;

  const float a0 = att[b * 2 + 0];
  const float a1 = att[b * 2 + 1];

  if (tid < 128) biasS[tid] = a0 * bc[m0 + tid] + a1 * be[m0 + tid];
  for (int k = tid; k < KTOT; k += 256) {
    const int ci = k / 25, r = k - ci * 25;
    const int kh = r / 5,  kw = r - kh * 5;
    koffAll[k] = ci * HW_IN + kh * WIN + kw;
  }

  // staging geometry: 512 tasks (row, k-octet), 2 per thread
  const int rowT = tid >> 2;         // 0..63 (second task: +64)
  const int oct  = (tid & 3) * 8;    // 0,8,16,24

  const float* xb = x + (size_t)b * (CIN * HW_IN);
  const int pA = p0 + rowT, pB = p0 + rowT + 64;
  const int ohA = pA / WO, owA = pA - ohA * WO;
  const int ohB = pB / WO, owB = pB - ohB * WO;
  const bool vA = pA < NPIX, vB = pB < NPIX;
  const float* xpA = xb + (ohA * 2) * WIN + owA * 2;
  const float* xpB = xb + (ohB * 2) * WIN + owB * 2;

  const float* wcr0 = wc + (size_t)(m0 + rowT) * KTOT + oct;
  const float* wer0 = we + (size_t)(m0 + rowT) * KTOT + oct;

  const f32x4 zero = {0.f, 0.f, 0.f, 0.f};
  f32x4 acc[4][4];
  #pragma unroll
  for (int i = 0; i < 4; ++i)
    #pragma unroll
    for (int j = 0; j < 4; ++j) acc[i][j] = zero;

  for (int k0 = 0; k0 < KTOT; k0 += 32) {
    __syncthreads();
    // -- A tile: on-the-fly aggregated weight (a0*Wc + a1*We) -> bf16 --
    #pragma unroll
    for (int t = 0; t < 2; ++t) {
      const float4* pc = (const float4*)(wcr0 + (size_t)t * 64 * KTOT + k0);
      const float4* pe = (const float4*)(wer0 + (size_t)t * 64 * KTOT + k0);
      float4 c0 = pc[0], c1 = pc[1];
      float4 e0 = pe[0], e1 = pe[1];
      bf16x8 hv;
      hv[0] = f2bf(a0 * c0.x + a1 * e0.x);
      hv[1] = f2bf(a0 * c0.y + a1 * e0.y);
      hv[2] = f2bf(a0 * c0.z + a1 * e0.z);
      hv[3] = f2bf(a0 * c0.w + a1 * e0.w);
      hv[4] = f2bf(a0 * c1.x + a1 * e1.x);
      hv[5] = f2bf(a0 * c1.y + a1 * e1.y);
      hv[6] = f2bf(a0 * c1.z + a1 * e1.z);
      hv[7] = f2bf(a0 * c1.w + a1 * e1.w);
      *(bf16x8*)&As[rowT + t * 64][oct] = hv;
    }
    // -- B tile: im2col gather via LDS offset table -> bf16 --
    const int4 ka = *(const int4*)&koffAll[k0 + oct];
    const int4 kb = *(const int4*)&koffAll[k0 + oct + 4];
    {
      bf16x8 hv = {0, 0, 0, 0, 0, 0, 0, 0};
      if (vA) {
        hv[0] = f2bf(xpA[ka.x]); hv[1] = f2bf(xpA[ka.y]);
        hv[2] = f2bf(xpA[ka.z]); hv[3] = f2bf(xpA[ka.w]);
        hv[4] = f2bf(xpA[kb.x]); hv[5] = f2bf(xpA[kb.y]);
        hv[6] = f2bf(xpA[kb.z]); hv[7] = f2bf(xpA[kb.w]);
      }
      *(bf16x8*)&Bs[rowT][oct] = hv;
    }
    {
      bf16x8 hv = {0, 0, 0, 0, 0, 0, 0, 0};
      if (vB) {
        hv[0] = f2bf(xpB[ka.x]); hv[1] = f2bf(xpB[ka.y]);
        hv[2] = f2bf(xpB[ka.z]); hv[3] = f2bf(xpB[ka.w]);
        hv[4] = f2bf(xpB[kb.x]); hv[5] = f2bf(xpB[kb.y]);
        hv[6] = f2bf(xpB[kb.z]); hv[7] = f2bf(xpB[kb.w]);
      }
      *(bf16x8*)&Bs[rowT + 64][oct] = hv;
    }
    __syncthreads();
    // -- fragments + MFMA: A[m=lm][k=quad*8+j], B[k=quad*8+j][n=lm] --
    bf16x8 af[4], bfv[4];
    #pragma unroll
    for (int i = 0; i < 4; ++i) af[i]  = *(const bf16x8*)&As[wm + i * 16 + lm][quad * 8];
    #pragma unroll
    for (int j = 0; j < 4; ++j) bfv[j] = *(const bf16x8*)&Bs[wn + j * 16 + lm][quad * 8];
    #pragma unroll
    for (int i = 0; i < 4; ++i)
      #pragma unroll
      for (int j = 0; j < 4; ++j)
        acc[i][j] = __builtin_amdgcn_mfma_f32_16x16x32_bf16(af[i], bfv[j], acc[i][j], 0, 0, 0);
  }

  // -- epilogue: D row = quad*4 + r, col = lm --
  float* outb = out + ((size_t)b * COUT + m0) * NPIX;
  #pragma unroll
  for (int j = 0; j < 4; ++j) {
    const int p = p0 + wn + j * 16 + lm;
    if (p < NPIX) {
      #pragma unroll
      for (int i = 0; i < 4; ++i) {
        #pragma unroll
        for (int r = 0; r < 4; ++r) {
          const int m = wm + i * 16 + quad * 4 + r;
          outb[(size_t)m * NPIX + p] = acc[i][j][r] + biasS[m];
        }
      }
    }
  }
}

extern "C" void kernel_launch(void* const* d_in, const int* in_sizes, int n_in,
                              void* d_out, int out_size, void* d_ws, size_t ws_size,
                              hipStream_t stream) {
  (void)in_sizes; (void)n_in; (void)out_size; (void)ws_size;
  const float* x  = (const float*)d_in[0];
  const float* wc = (const float*)d_in[1];
  const float* bc = (const float*)d_in[2];
  const float* we = (const float*)d_in[3];
  const float* be = (const float*)d_in[4];
  const float* w1 = (const float*)d_in[5];
  const float* w2 = (const float*)d_in[6];
  float* out = (float*)d_out;

  float* att    = (float*)d_ws;   // 256 floats
  float* pooled = att + 256;      // 12288 floats

  pool_kernel<<<dim3(CIN, NB), 256, 0, stream>>>(x, pooled);
  attn_kernel<<<NB, 64, 0, stream>>>(pooled, w1, w2, att);
  conv_kernel<<<dim3(8, 2, NB), 256, 0, stream>>>(x, wc, we, bc, be, att, out);
}